// Round 13
// baseline (15.281 us; speedup 1.0000x reference)
//
#include <hip/hip_runtime.h>
#include <math.h>

#define NBLK 1024   // main kernel: 262144 threads, 1 column each (proven topology)
#define NTHR 256

constexpr float LOG_K_F = 2.7725887222397811f;   // log(16)
constexpr float LOG_EPS = -69.077552789821368f;  // log(1e-30)
constexpr float LOG_001 = -6.9077552789821368f;  // log(0.001)

struct BC {
    float rb;        // exp(ev_oth - ev_cat): gumbel ratio threshold
    float qs, qo, eqs, eqo;
    float evt_cat, evt_oth;
    float C1;        // exp(dt1 - logK) (0 if t==0)
    float e_ct1;     // exp(ct1) (1 if t==0)
    float klp;       // prior-KL per-column constant
    int t0;
};

__device__ __forceinline__ float lae_f(float a, float b) {
    float m = fmaxf(a, b);
    return m + __logf(1.f + __expf(-fabsf(a - b)));
}

// Closed-form cosine-beta schedule constants (validated absmax 0.0 R4-R12).
// ac_raw(x) = sin^2(W*(1000-x)), W=pi/2016; log_cum telescopes; t=999 is the
// only beta-clip (beta=0.999).
__device__ __forceinline__ BC make_bc(int tb) {
    const float W = (float)(3.14159265358979323846 / 2016.0);
    const float s1000 = __sinf(W * 1000.f);
    const float ls1000 = __logf(s1000);
    const float inv2 = 1.f / (s1000 * s1000);

    const bool t999 = (tb == 999);
    const bool t0 = (tb == 0);
    const float ftb = (float)tb;

    const float ftbc = t999 ? 998.f : ftb;
    float ct = 2.f * (__logf(__sinf(W * (999.f - ftbc))) - ls1000);
    if (t999) ct += LOG_001;
    float dt = __logf(__sinf(W * (1999.f - ftb)) * __sinf(W * (ftb + 1.f)) * inv2 + 1e-40f);
    float at, btv;
    if (t999) {
        at = LOG_001;
        btv = __logf(0.999f);
    } else {
        const float s0 = __sinf(W * (1000.f - ftb));
        at = 2.f * (__logf(__sinf(W * (999.f - ftb))) - __logf(s0));
        btv = __logf(__sinf(W) * __sinf(W * (1999.f - 2.f * ftb)) / (s0 * s0) + 1e-40f);
    }
    float ct1 = 0.f, dt1 = 0.f;
    if (!t0) {
        ct1 = 2.f * (__logf(__sinf(W * (1000.f - ftb))) - ls1000);
        dt1 = __logf(__sinf(W * (2000.f - ftb)) * __sinf(W * ftb) * inv2 + 1e-40f);
    }

    const float ev_cat = lae_f(ct, dt - LOG_K_F);
    const float ev_oth = lae_f(LOG_EPS + ct, dt - LOG_K_F);

    BC c;
    c.t0 = t0 ? 1 : 0;
    c.rb = __expf(ev_oth - ev_cat);
    c.qs = lae_f(at, btv - LOG_K_F);
    c.qo = lae_f(LOG_EPS + at, btv - LOG_K_F);
    c.eqs = __expf(c.qs);
    c.eqo = __expf(c.qo);
    c.evt_cat = t0 ? 0.f : lae_f(ct1, dt1 - LOG_K_F);
    c.evt_oth = t0 ? LOG_EPS : lae_f(LOG_EPS + ct1, dt1 - LOG_K_F);
    c.C1 = t0 ? 0.f : __expf(dt1 - LOG_K_F);
    c.e_ct1 = t0 ? 1.f : __expf(ct1);
    const float cT = 2.f * (__logf(__sinf(W)) - ls1000) + LOG_001;
    const float dT = 0.f;
    const float vc = lae_f(cT, dT - LOG_K_F);
    const float vo = lae_f(LOG_EPS + cT, dT - LOG_K_F);
    c.klp = __expf(vc) * (vc + LOG_K_F) + 15.f * __expf(vo) * (vo + LOG_K_F);
    return c;
}

// Kernel 1: R12's proven body. BC computed per block by ONE lane into LDS;
// __launch_bounds__(,4) grants a 128-VGPR budget (16 waves/CU) so the
// compiler cannot repeat the R3/R4 spill. MSE loads hoisted into the front
// load cluster (they previously added an exposed ~900-cycle tail for the
// 512 active blocks).
__global__ __launch_bounds__(NTHR, 4) void main_kernel(
        const int*   __restrict__ cats,     // [64,16,256]
        const float* __restrict__ logits,   // [64,256,256]
        const float* __restrict__ mnum,     // [64,8,256]
        const float* __restrict__ nnum,     // [64,8,256]
        const float* __restrict__ unoise,   // [64,256,256]
        const int*   __restrict__ tarr,     // [64]
        float*       __restrict__ partials) // [NBLK]
{
    __shared__ BC sbc;
    const int tid = blockIdx.x * NTHR + threadIdx.x;  // 0..262143
    const int bi  = tid >> 8;                         // b*16 + i (== blockIdx.x)
    const int b   = bi >> 4;                          // block-uniform

    if (threadIdx.x == 0) sbc = make_bc(tarr[b]);

    const int cat = cats[tid];
    const size_t base = (size_t)bi * 4096 + (tid & 255);

    // ---- load cluster: all global reads issued up front (overlaps BC calc) ----
    float uu[16], lg[16];
#pragma unroll
    for (int k = 0; k < 16; ++k) {
        uu[k] = unoise[base + (size_t)k * 256];
        lg[k] = logits[base + (size_t)k * 256];
    }
    float mnv = 0.f, nnv = 0.f;
    if (tid < 64 * 8 * 256) {   // block-uniform branch (blocks 0..511)
        mnv = mnum[tid];
        nnv = nnum[tid];
    }
    __syncthreads();
    const BC c = sbc;

    // ---- softmax exponentials + gumbel-argmax candidates ----
    float ek[16];
    float slg = 0.f, u_cat = 0.f, umax = -1.f;
    int kmx = 0;
#pragma unroll
    for (int k = 0; k < 16; ++k) {
        ek[k] = __expf(lg[k]);
        slg += ek[k];
        const bool ic = (k == cat);
        u_cat = ic ? uu[k] : u_cat;
        const bool upd = (!ic) && (uu[k] > umax);
        umax = upd ? uu[k] : umax;
        kmx  = upd ? k : kmx;
    }
    // gumbel-argmax in ratio form: v_c > v_o  <=>  e_o > e_c * rb
    const float e_c = -__logf(u_cat + 1e-30f) + 1e-30f;
    const float e_o = -__logf(umax  + 1e-30f) + 1e-30f;
    const float thr = e_c * c.rb;
    const int samp = (e_o > thr) ? cat : ((e_o < thr) ? kmx : min(cat, kmx));

    // ---- model posterior in exp space ----
    const float scale = c.e_ct1 * __builtin_amdgcn_rcpf(slg);
    float ve_[16];
    float S_all = 0.f;
#pragma unroll
    for (int k = 0; k < 16; ++k) {
        ve_[k] = ek[k] * scale + c.C1;   // exp(evm_k), in (0, 1.1]
        S_all += ve_[k];
    }
    // sum_le via 4 grouped products (4 logs instead of 16); group product
    // >= (1e-7)^4 = 1e-28 > FLT_MIN, no underflow.
    float sum_le = 0.f;
#pragma unroll
    for (int gq = 0; gq < 4; ++gq) {
        const float p = ve_[4*gq] * ve_[4*gq+1] * ve_[4*gq+2] * ve_[4*gq+3];
        sum_le += __logf(p);
    }
    float ve_cat = ve_[0], ve_samp = ve_[0];
#pragma unroll
    for (int k = 0; k < 16; ++k) {
        ve_cat  = (k == cat)  ? ve_[k] : ve_cat;
        ve_samp = (k == samp) ? ve_[k] : ve_samp;
    }
    const float le_cat  = __logf(ve_cat);
    const float le_samp = __logf(ve_samp);
    const float sum_m = c.eqo * (S_all - ve_samp) + c.eqs * ve_samp;
    const float lsem  = __logf(sum_m);

    // ---- true posterior: <=3 distinct values, closed-form ----
    const bool  eq  = (cat == samp);
    const float q_c = eq ? c.qs : c.qo;
    const float w_s = eq ? 0.f : 1.f;
    const float n_o = eq ? 15.f : 14.f;
    const float a  = c.evt_cat + q_c;
    const float bs = c.evt_oth + c.qs;
    const float cc = c.evt_oth + c.qo;
    const float m  = fmaxf(a, fmaxf(bs, cc));
    const float ea = __expf(a - m), eb = __expf(bs - m), ecx = __expf(cc - m);
    const float D  = ea + w_s * eb + n_o * ecx;
    const float lset = m + __logf(D);
    const float rcpD = __builtin_amdgcn_rcpf(D);
    const float lt_c = a - lset, lt_s = bs - lset, lt_o = cc - lset;
    const float p_c = ea * rcpD, p_s = eb * rcpD, p_o = ecx * rcpD;

    const float sum_p_lt = p_c * lt_c + w_s * p_s * lt_s + n_o * p_o * lt_o;
    const float lm_cat  = le_cat  + q_c  - lsem;
    const float lm_samp = le_samp + c.qs - lsem;
    const float sum_lm_oth = (sum_le - le_cat - w_s * le_samp) + n_o * (c.qo - lsem);
    const float sum_p_lm = p_c * lm_cat + w_s * p_s * lm_samp + p_o * sum_lm_oth;
    const float kl  = sum_p_lt - sum_p_lm;
    const float nll = -lm_cat;

    float acc = ((c.t0 ? nll : kl) + c.klp) * (0.5f / 64.0f);

    // ---- numeric branch MSE (loads hoisted; zeros for inactive blocks) ----
    {
        const float d = mnv - nnv;
        acc += d * d * (0.5f / 131072.f);
    }

    // ---- block reduction ----
    for (int o = 32; o > 0; o >>= 1) acc += __shfl_down(acc, o, 64);
    __shared__ float wsum[4];
    const int wave = threadIdx.x >> 6, lane = threadIdx.x & 63;
    if (lane == 0) wsum[wave] = acc;
    __syncthreads();
    if (threadIdx.x == 0)
        partials[blockIdx.x] = wsum[0] + wsum[1] + wsum[2] + wsum[3];
}

// Kernel 2: deterministic final reduce — 256 threads x float4 (fewer waves
// in a launch-bound kernel). Fence-free, atomic-free (both bench-rejected:
// fence +17us, 1024 same-address atomics +9us).
__global__ void reduce_kernel(const float4* __restrict__ partials,
                              float* __restrict__ out) {
    const float4 v4 = partials[threadIdx.x];   // 256 x float4 = 1024 floats
    float v = (v4.x + v4.y) + (v4.z + v4.w);
    for (int o = 32; o > 0; o >>= 1) v += __shfl_down(v, o, 64);
    __shared__ float wsum[4];
    const int wave = threadIdx.x >> 6, lane = threadIdx.x & 63;
    if (lane == 0) wsum[wave] = v;
    __syncthreads();
    if (threadIdx.x == 0)
        out[0] = (wsum[0] + wsum[1]) + (wsum[2] + wsum[3]);
}

extern "C" void kernel_launch(void* const* d_in, const int* in_sizes, int n_in,
                              void* d_out, int out_size, void* d_ws, size_t ws_size,
                              hipStream_t stream) {
    const int*   cats   = (const int*)  d_in[0];
    const float* logits = (const float*)d_in[1];
    const float* mnum   = (const float*)d_in[2];
    const float* nnum   = (const float*)d_in[3];
    const float* unoise = (const float*)d_in[4];
    const int*   tarr   = (const int*)  d_in[5];

    float* partials = (float*)d_ws;

    main_kernel<<<NBLK, NTHR, 0, stream>>>(cats, logits, mnum, nnum, unoise,
                                           tarr, partials);
    reduce_kernel<<<1, 256, 0, stream>>>((const float4*)partials, (float*)d_out);
}

// Round 14
// 14.013 us; speedup vs baseline: 1.0905x; 1.0905x over previous
//
#include <hip/hip_runtime.h>
#include <math.h>

#define NBLK 1024   // main kernel: 262144 threads, 1 column each (proven topology)
#define NTHR 256

constexpr float LOG_K_F = 2.7725887222397811f;   // log(16)
constexpr float LOG_EPS = -69.077552789821368f;  // log(1e-30)
constexpr float LOG_001 = -6.9077552789821368f;  // log(0.001)

struct BC {
    float rb;        // exp(ev_oth - ev_cat): gumbel ratio threshold
    float qs, qo, eqs, eqo;
    float evt_cat, evt_oth;
    float C1;        // exp(dt1 - logK) (0 if t==0)
    float e_ct1;     // exp(ct1) (1 if t==0)
    float klp;       // prior-KL per-column constant
    int t0;
};

__device__ __forceinline__ float lae_f(float a, float b) {
    float m = fmaxf(a, b);
    return m + __logf(1.f + __expf(-fabsf(a - b)));
}

// Closed-form cosine-beta schedule constants (validated absmax 0.0 R4-R13).
// ac_raw(x) = sin^2(W*(1000-x)), W=pi/2016; log_cum telescopes; t=999 is the
// only beta-clip (beta=0.999).
__device__ __forceinline__ BC make_bc(int tb) {
    const float W = (float)(3.14159265358979323846 / 2016.0);
    const float s1000 = __sinf(W * 1000.f);
    const float ls1000 = __logf(s1000);
    const float inv2 = 1.f / (s1000 * s1000);

    const bool t999 = (tb == 999);
    const bool t0 = (tb == 0);
    const float ftb = (float)tb;

    const float ftbc = t999 ? 998.f : ftb;
    float ct = 2.f * (__logf(__sinf(W * (999.f - ftbc))) - ls1000);
    if (t999) ct += LOG_001;
    float dt = __logf(__sinf(W * (1999.f - ftb)) * __sinf(W * (ftb + 1.f)) * inv2 + 1e-40f);
    float at, btv;
    if (t999) {
        at = LOG_001;
        btv = __logf(0.999f);
    } else {
        const float s0 = __sinf(W * (1000.f - ftb));
        at = 2.f * (__logf(__sinf(W * (999.f - ftb))) - __logf(s0));
        btv = __logf(__sinf(W) * __sinf(W * (1999.f - 2.f * ftb)) / (s0 * s0) + 1e-40f);
    }
    float ct1 = 0.f, dt1 = 0.f;
    if (!t0) {
        ct1 = 2.f * (__logf(__sinf(W * (1000.f - ftb))) - ls1000);
        dt1 = __logf(__sinf(W * (2000.f - ftb)) * __sinf(W * ftb) * inv2 + 1e-40f);
    }

    const float ev_cat = lae_f(ct, dt - LOG_K_F);
    const float ev_oth = lae_f(LOG_EPS + ct, dt - LOG_K_F);

    BC c;
    c.t0 = t0 ? 1 : 0;
    c.rb = __expf(ev_oth - ev_cat);
    c.qs = lae_f(at, btv - LOG_K_F);
    c.qo = lae_f(LOG_EPS + at, btv - LOG_K_F);
    c.eqs = __expf(c.qs);
    c.eqo = __expf(c.qo);
    c.evt_cat = t0 ? 0.f : lae_f(ct1, dt1 - LOG_K_F);
    c.evt_oth = t0 ? LOG_EPS : lae_f(LOG_EPS + ct1, dt1 - LOG_K_F);
    c.C1 = t0 ? 0.f : __expf(dt1 - LOG_K_F);
    c.e_ct1 = t0 ? 1.f : __expf(ct1);
    const float cT = 2.f * (__logf(__sinf(W)) - ls1000) + LOG_001;
    const float dT = 0.f;
    const float vc = lae_f(cT, dT - LOG_K_F);
    const float vo = lae_f(LOG_EPS + cT, dT - LOG_K_F);
    c.klp = __expf(vc) * (vc + LOG_K_F) + 15.f * __expf(vo) * (vo + LOG_K_F);
    return c;
}

// Kernel 1: R12's proven body (13.4us measured). BC computed per block by
// ONE lane into LDS; __launch_bounds__(,4) grants a 128-VGPR budget
// (16 waves/CU) so the compiler cannot repeat the R3/R4 spill.
__global__ __launch_bounds__(NTHR, 4) void main_kernel(
        const int*   __restrict__ cats,     // [64,16,256]
        const float* __restrict__ logits,   // [64,256,256]
        const float* __restrict__ mnum,     // [64,8,256]
        const float* __restrict__ nnum,     // [64,8,256]
        const float* __restrict__ unoise,   // [64,256,256]
        const int*   __restrict__ tarr,     // [64]
        float*       __restrict__ partials) // [NBLK]
{
    __shared__ BC sbc;
    const int tid = blockIdx.x * NTHR + threadIdx.x;  // 0..262143
    const int bi  = tid >> 8;                         // b*16 + i (== blockIdx.x)
    const int b   = bi >> 4;                          // block-uniform

    if (threadIdx.x == 0) sbc = make_bc(tarr[b]);

    const int cat = cats[tid];
    const size_t base = (size_t)bi * 4096 + (tid & 255);

    // ---- load cluster: 32 independent coalesced loads (overlaps BC calc) ----
    float uu[16], lg[16];
#pragma unroll
    for (int k = 0; k < 16; ++k) {
        uu[k] = unoise[base + (size_t)k * 256];
        lg[k] = logits[base + (size_t)k * 256];
    }
    __syncthreads();
    const BC c = sbc;

    // ---- softmax exponentials + gumbel-argmax candidates ----
    float ek[16];
    float slg = 0.f, u_cat = 0.f, umax = -1.f;
    int kmx = 0;
#pragma unroll
    for (int k = 0; k < 16; ++k) {
        ek[k] = __expf(lg[k]);
        slg += ek[k];
        const bool ic = (k == cat);
        u_cat = ic ? uu[k] : u_cat;
        const bool upd = (!ic) && (uu[k] > umax);
        umax = upd ? uu[k] : umax;
        kmx  = upd ? k : kmx;
    }
    // gumbel-argmax in ratio form: v_c > v_o  <=>  e_o > e_c * rb
    const float e_c = -__logf(u_cat + 1e-30f) + 1e-30f;
    const float e_o = -__logf(umax  + 1e-30f) + 1e-30f;
    const float thr = e_c * c.rb;
    const int samp = (e_o > thr) ? cat : ((e_o < thr) ? kmx : min(cat, kmx));

    // ---- model posterior in exp space ----
    const float scale = c.e_ct1 * __builtin_amdgcn_rcpf(slg);
    float ve_[16];
    float S_all = 0.f;
#pragma unroll
    for (int k = 0; k < 16; ++k) {
        ve_[k] = ek[k] * scale + c.C1;   // exp(evm_k), in (0, 1.1]
        S_all += ve_[k];
    }
    // sum_le via 4 grouped products (4 logs instead of 16); group product
    // >= (1e-7)^4 = 1e-28 > FLT_MIN, no underflow.
    float sum_le = 0.f;
#pragma unroll
    for (int gq = 0; gq < 4; ++gq) {
        const float p = ve_[4*gq] * ve_[4*gq+1] * ve_[4*gq+2] * ve_[4*gq+3];
        sum_le += __logf(p);
    }
    float ve_cat = ve_[0], ve_samp = ve_[0];
#pragma unroll
    for (int k = 0; k < 16; ++k) {
        ve_cat  = (k == cat)  ? ve_[k] : ve_cat;
        ve_samp = (k == samp) ? ve_[k] : ve_samp;
    }
    const float le_cat  = __logf(ve_cat);
    const float le_samp = __logf(ve_samp);
    const float sum_m = c.eqo * (S_all - ve_samp) + c.eqs * ve_samp;
    const float lsem  = __logf(sum_m);

    // ---- true posterior: <=3 distinct values, closed-form ----
    const bool  eq  = (cat == samp);
    const float q_c = eq ? c.qs : c.qo;
    const float w_s = eq ? 0.f : 1.f;
    const float n_o = eq ? 15.f : 14.f;
    const float a  = c.evt_cat + q_c;
    const float bs = c.evt_oth + c.qs;
    const float cc = c.evt_oth + c.qo;
    const float m  = fmaxf(a, fmaxf(bs, cc));
    const float ea = __expf(a - m), eb = __expf(bs - m), ecx = __expf(cc - m);
    const float D  = ea + w_s * eb + n_o * ecx;
    const float lset = m + __logf(D);
    const float rcpD = __builtin_amdgcn_rcpf(D);
    const float lt_c = a - lset, lt_s = bs - lset, lt_o = cc - lset;
    const float p_c = ea * rcpD, p_s = eb * rcpD, p_o = ecx * rcpD;

    const float sum_p_lt = p_c * lt_c + w_s * p_s * lt_s + n_o * p_o * lt_o;
    const float lm_cat  = le_cat  + q_c  - lsem;
    const float lm_samp = le_samp + c.qs - lsem;
    const float sum_lm_oth = (sum_le - le_cat - w_s * le_samp) + n_o * (c.qo - lsem);
    const float sum_p_lm = p_c * lm_cat + w_s * p_s * lm_samp + p_o * sum_lm_oth;
    const float kl  = sum_p_lt - sum_p_lm;
    const float nll = -lm_cat;

    float acc = ((c.t0 ? nll : kl) + c.klp) * (0.5f / 64.0f);

    // ---- numeric branch MSE (tids 0..131071) ----
    if (tid < 64 * 8 * 256) {
        const float d = mnum[tid] - nnum[tid];
        acc += d * d * (0.5f / 131072.f);
    }

    // ---- block reduction ----
    for (int o = 32; o > 0; o >>= 1) acc += __shfl_down(acc, o, 64);
    __shared__ float wsum[4];
    const int wave = threadIdx.x >> 6, lane = threadIdx.x & 63;
    if (lane == 0) wsum[wave] = acc;
    __syncthreads();
    if (threadIdx.x == 0)
        partials[blockIdx.x] = wsum[0] + wsum[1] + wsum[2] + wsum[3];
}

// Kernel 2: deterministic final reduce (graph edge orders it; fence-free,
// atomic-free -- both bench-rejected: fence +17us, same-address atomics +9us).
__global__ void reduce_kernel(const float* __restrict__ partials,
                              float* __restrict__ out) {
    float v = partials[threadIdx.x];   // NBLK=1024 threads exactly
    for (int o = 32; o > 0; o >>= 1) v += __shfl_down(v, o, 64);
    __shared__ float wsum[16];
    const int wave = threadIdx.x >> 6, lane = threadIdx.x & 63;
    if (lane == 0) wsum[wave] = v;
    __syncthreads();
    if (threadIdx.x == 0) {
        float s = 0.f;
#pragma unroll
        for (int w = 0; w < 16; ++w) s += wsum[w];
        out[0] = s;
    }
}

extern "C" void kernel_launch(void* const* d_in, const int* in_sizes, int n_in,
                              void* d_out, int out_size, void* d_ws, size_t ws_size,
                              hipStream_t stream) {
    const int*   cats   = (const int*)  d_in[0];
    const float* logits = (const float*)d_in[1];
    const float* mnum   = (const float*)d_in[2];
    const float* nnum   = (const float*)d_in[3];
    const float* unoise = (const float*)d_in[4];
    const int*   tarr   = (const int*)  d_in[5];

    float* partials = (float*)d_ws;

    main_kernel<<<NBLK, NTHR, 0, stream>>>(cats, logits, mnum, nnum, unoise,
                                           tarr, partials);
    reduce_kernel<<<1, NBLK, 0, stream>>>(partials, (float*)d_out);
}